// Round 1
// baseline (3024.406 us; speedup 1.0000x reference)
//
#include <hip/hip_runtime.h>

#define N_NODES 50000
#define IN_CH   128
#define HID_CH  256
#define OUT_CH  128

#define TM 64
#define TN 64
#define TK 32
#define LDT (TM + 4)   // padded leading dim for transposed LDS tiles (keeps 16B align: 68*4=272)

// ---------------------------------------------------------------------------
// Edge scatter: for each edge e, agg[dst[e]] += feat[src[e]] (128 channels).
// 32 threads per edge, 4 channels each (float4 gather, 4 scalar atomics).
// Optionally accumulates degree (layer 1 only).
// ---------------------------------------------------------------------------
__global__ __launch_bounds__(256) void scatter_add_kernel(
    const float* __restrict__ feat, const int* __restrict__ src,
    const int* __restrict__ dst, float* __restrict__ agg,
    float* __restrict__ deg, int E)
{
    int t  = blockIdx.x * 256 + threadIdx.x;
    int e  = t >> 5;
    int lc = t & 31;
    if (e >= E) return;
    int s = src[e];
    int d = dst[e];
    if ((unsigned)s >= (unsigned)N_NODES || (unsigned)d >= (unsigned)N_NODES) return;
    const float4 v = *reinterpret_cast<const float4*>(feat + (size_t)s * 128 + lc * 4);
    float* a = agg + (size_t)d * 128 + lc * 4;
    atomicAdd(a + 0, v.x);
    atomicAdd(a + 1, v.y);
    atomicAdd(a + 2, v.z);
    atomicAdd(a + 3, v.w);
    if (deg != nullptr && lc == 0) atomicAdd(deg + d, 1.0f);
}

__global__ __launch_bounds__(256) void invdeg_kernel(
    const float* __restrict__ deg, float* __restrict__ invdeg, int n)
{
    int i = blockIdx.x * 256 + threadIdx.x;
    if (i < n) invdeg[i] = 1.0f / fmaxf(deg[i], 1.0f);
}

// ---------------------------------------------------------------------------
// Load a 64x32 tile of row-major [rows][K] matrix g into LDS transposed as
// s[kk][r] (kk in [0,TK), r in [0,64)). Optional per-row scale (invdeg).
// 256 threads, 2 float4 global loads each, 4 scalar LDS stores per float4.
// ---------------------------------------------------------------------------
__device__ __forceinline__ void load_tile_T(
    const float* __restrict__ g, float* __restrict__ s,
    int K, int rowBase, int kBase, int maxRow,
    const float* __restrict__ rowScale, int tid)
{
#pragma unroll
    for (int it = 0; it < 2; ++it) {
        int idx = tid + it * 256;        // float4 index within tile (0..511)
        int r   = idx >> 3;              // tile row 0..63
        int c4  = (idx & 7) << 2;        // k offset 0..28
        int row = rowBase + r;
        if (row >= maxRow) row = maxRow - 1;   // clamp: loads stay in-bounds, stores are guarded later
        const float4 v = *reinterpret_cast<const float4*>(g + (size_t)row * K + kBase + c4);
        float sc = rowScale ? rowScale[row] : 1.0f;
        float* p0 = s + (size_t)c4 * LDT + r;
        p0[0 * LDT] = v.x * sc;
        p0[1 * LDT] = v.y * sc;
        p0[2 * LDT] = v.z * sc;
        p0[3 * LDT] = v.w * sc;
    }
}

// ---------------------------------------------------------------------------
// GEMM1: h = relu( (agg1 * invdeg) @ W1l^T + b1l + x @ W1r^T )
// A: [N,128] row-major, B: [256,128] row-major (so C[m][n] = sum_k A[m][k]*B[n][k])
// ---------------------------------------------------------------------------
__global__ __launch_bounds__(256) void gemm1_kernel(
    const float* __restrict__ agg1, const float* __restrict__ invdeg,
    const float* __restrict__ x,    const float* __restrict__ W1l,
    const float* __restrict__ W1r,  const float* __restrict__ b1l,
    float* __restrict__ h)
{
    __shared__ float As[TK][LDT];
    __shared__ float Bs[TK][LDT];

    const int tid = threadIdx.x;
    const int tx = tid & 15, ty = tid >> 4;
    const int rowBase = blockIdx.x * TM;
    const int colBase = blockIdx.y * TN;

    float acc[4][4] = {};

    for (int op = 0; op < 2; ++op) {
        const float* A  = op ? x : agg1;
        const float* B  = op ? W1r : W1l;
        const float* rs = op ? nullptr : invdeg;
        for (int kb = 0; kb < IN_CH; kb += TK) {
            load_tile_T(A, &As[0][0], IN_CH, rowBase, kb, N_NODES, rs, tid);
            load_tile_T(B, &Bs[0][0], IN_CH, colBase, kb, HID_CH, nullptr, tid);
            __syncthreads();
#pragma unroll
            for (int kk = 0; kk < TK; ++kk) {
                float a[4], b[4];
                *reinterpret_cast<float4*>(a) = *reinterpret_cast<const float4*>(&As[kk][ty * 4]);
                *reinterpret_cast<float4*>(b) = *reinterpret_cast<const float4*>(&Bs[kk][tx * 4]);
#pragma unroll
                for (int i = 0; i < 4; ++i)
#pragma unroll
                    for (int j = 0; j < 4; ++j)
                        acc[i][j] = fmaf(a[i], b[j], acc[i][j]);
            }
            __syncthreads();
        }
    }

    float bias[4];
    *reinterpret_cast<float4*>(bias) = *reinterpret_cast<const float4*>(b1l + colBase + tx * 4);
#pragma unroll
    for (int i = 0; i < 4; ++i) {
        int row = rowBase + ty * 4 + i;
        if (row < N_NODES) {
            float4 o;
            o.x = fmaxf(acc[i][0] + bias[0], 0.0f);
            o.y = fmaxf(acc[i][1] + bias[1], 0.0f);
            o.z = fmaxf(acc[i][2] + bias[2], 0.0f);
            o.w = fmaxf(acc[i][3] + bias[3], 0.0f);
            *reinterpret_cast<float4*>(h + (size_t)row * HID_CH + colBase + tx * 4) = o;
        }
    }
}

// ---------------------------------------------------------------------------
// GEMM2 (fused): p = h @ W2l^T ; out0 = h @ W2r^T + b2l
// Reads h once, produces both. K = 256.
// ---------------------------------------------------------------------------
__global__ __launch_bounds__(256) void gemm2_kernel(
    const float* __restrict__ h,   const float* __restrict__ W2l,
    const float* __restrict__ W2r, const float* __restrict__ b2l,
    float* __restrict__ p, float* __restrict__ out)
{
    __shared__ float As[TK][LDT];
    __shared__ float Bl[TK][LDT];
    __shared__ float Br[TK][LDT];

    const int tid = threadIdx.x;
    const int tx = tid & 15, ty = tid >> 4;
    const int rowBase = blockIdx.x * TM;
    const int colBase = blockIdx.y * TN;

    float accl[4][4] = {};
    float accr[4][4] = {};

    for (int kb = 0; kb < HID_CH; kb += TK) {
        load_tile_T(h,   &As[0][0], HID_CH, rowBase, kb, N_NODES, nullptr, tid);
        load_tile_T(W2l, &Bl[0][0], HID_CH, colBase, kb, OUT_CH, nullptr, tid);
        load_tile_T(W2r, &Br[0][0], HID_CH, colBase, kb, OUT_CH, nullptr, tid);
        __syncthreads();
#pragma unroll
        for (int kk = 0; kk < TK; ++kk) {
            float a[4], bl[4], br[4];
            *reinterpret_cast<float4*>(a)  = *reinterpret_cast<const float4*>(&As[kk][ty * 4]);
            *reinterpret_cast<float4*>(bl) = *reinterpret_cast<const float4*>(&Bl[kk][tx * 4]);
            *reinterpret_cast<float4*>(br) = *reinterpret_cast<const float4*>(&Br[kk][tx * 4]);
#pragma unroll
            for (int i = 0; i < 4; ++i)
#pragma unroll
                for (int j = 0; j < 4; ++j) {
                    accl[i][j] = fmaf(a[i], bl[j], accl[i][j]);
                    accr[i][j] = fmaf(a[i], br[j], accr[i][j]);
                }
        }
        __syncthreads();
    }

    float bias[4];
    *reinterpret_cast<float4*>(bias) = *reinterpret_cast<const float4*>(b2l + colBase + tx * 4);
#pragma unroll
    for (int i = 0; i < 4; ++i) {
        int row = rowBase + ty * 4 + i;
        if (row < N_NODES) {
            *reinterpret_cast<float4*>(p + (size_t)row * OUT_CH + colBase + tx * 4) =
                *reinterpret_cast<float4*>(accl[i]);
            float4 o;
            o.x = accr[i][0] + bias[0];
            o.y = accr[i][1] + bias[1];
            o.z = accr[i][2] + bias[2];
            o.w = accr[i][3] + bias[3];
            *reinterpret_cast<float4*>(out + (size_t)row * OUT_CH + colBase + tx * 4) = o;
        }
    }
}

// ---------------------------------------------------------------------------
// out += agg2 * invdeg[row]   (the mean(p) term of layer 2)
// ---------------------------------------------------------------------------
__global__ __launch_bounds__(256) void finalize_kernel(
    const float* __restrict__ agg2, const float* __restrict__ invdeg,
    float* __restrict__ out)
{
    int i4 = blockIdx.x * 256 + threadIdx.x;          // float4 index
    if (i4 >= N_NODES * OUT_CH / 4) return;
    int m = i4 >> 5;                                   // / (128/4)
    float s = invdeg[m];
    float4 a = reinterpret_cast<const float4*>(agg2)[i4];
    float4 o = reinterpret_cast<float4*>(out)[i4];
    o.x = fmaf(a.x, s, o.x);
    o.y = fmaf(a.y, s, o.y);
    o.z = fmaf(a.z, s, o.z);
    o.w = fmaf(a.w, s, o.w);
    reinterpret_cast<float4*>(out)[i4] = o;
}

extern "C" void kernel_launch(void* const* d_in, const int* in_sizes, int n_in,
                              void* d_out, int out_size, void* d_ws, size_t ws_size,
                              hipStream_t stream)
{
    const float* x   = (const float*)d_in[0];
    const int*   ei  = (const int*)d_in[1];
    const float* W1l = (const float*)d_in[2];
    const float* b1l = (const float*)d_in[3];
    const float* W1r = (const float*)d_in[4];
    const float* W2l = (const float*)d_in[5];
    const float* b2l = (const float*)d_in[6];
    const float* W2r = (const float*)d_in[7];

    const int E = in_sizes[1] / 2;
    const int* src = ei;
    const int* dst = ei + E;

    // Workspace layout (agg1 reused as p; agg2 overlaps h, which is dead by then)
    char* ws = (char*)d_ws;
    size_t off = 0;
    float* agg1   = (float*)(ws + off); off += (size_t)N_NODES * IN_CH  * 4;  // 25.6 MB
    float* h      = (float*)(ws + off); off += (size_t)N_NODES * HID_CH * 4;  // 51.2 MB
    float* deg    = (float*)(ws + off); off += (size_t)N_NODES * 4;
    float* invdeg = (float*)(ws + off); off += (size_t)N_NODES * 4;
    float* p    = agg1;   // agg1 dead after gemm1
    float* agg2 = h;      // h dead after gemm2 (memset ordered after gemm2 on stream)
    float* out  = (float*)d_out;

    const int scatterBlocks = (E * 32 + 255) / 256;

    // Layer 1
    hipMemsetAsync(agg1, 0, (size_t)N_NODES * IN_CH * 4, stream);
    hipMemsetAsync(deg,  0, (size_t)N_NODES * 4, stream);
    scatter_add_kernel<<<scatterBlocks, 256, 0, stream>>>(x, src, dst, agg1, deg, E);
    invdeg_kernel<<<(N_NODES + 255) / 256, 256, 0, stream>>>(deg, invdeg, N_NODES);
    gemm1_kernel<<<dim3((N_NODES + TM - 1) / TM, HID_CH / TN), 256, 0, stream>>>(
        agg1, invdeg, x, W1l, W1r, b1l, h);

    // Layer 2 (transform-then-aggregate: mean(h)@W2l^T == mean(h@W2l^T))
    gemm2_kernel<<<dim3((N_NODES + TM - 1) / TM, OUT_CH / TN), 256, 0, stream>>>(
        h, W2l, W2r, b2l, p, out);
    hipMemsetAsync(agg2, 0, (size_t)N_NODES * OUT_CH * 4, stream);
    scatter_add_kernel<<<scatterBlocks, 256, 0, stream>>>(p, src, dst, agg2, nullptr, E);
    finalize_kernel<<<(N_NODES * OUT_CH / 4 + 255) / 256, 256, 0, stream>>>(agg2, invdeg, out);
}

// Round 2
// 476.220 us; speedup vs baseline: 6.3509x; 6.3509x over previous
//
#include <hip/hip_runtime.h>

#define N_NODES 50000
#define IN_CH   128
#define HID_CH  256
#define OUT_CH  128

#define TM 64
#define TN 64
#define TK 32
#define LDT (TM + 4)   // padded leading dim for transposed LDS tiles

#define SCAN_B 256

// ---------------------------------------------------------------------------
// CSR build: histogram of dst, exclusive scan -> rowptr, cursor fill -> colidx
// ---------------------------------------------------------------------------
__global__ __launch_bounds__(256) void hist_kernel(
    const int* __restrict__ dst, int* __restrict__ degi, int E)
{
    int e = blockIdx.x * 256 + threadIdx.x;
    if (e >= E) return;
    int d = dst[e];
    if ((unsigned)d < (unsigned)N_NODES) atomicAdd(&degi[d], 1);
}

// Block-level exclusive scan of degi into rowptr (partial), block sums out.
__global__ __launch_bounds__(SCAN_B) void scan1_kernel(
    const int* __restrict__ degi, int* __restrict__ rowptr,
    int* __restrict__ bsum, int n)
{
    __shared__ int s[SCAN_B];
    int i = blockIdx.x * SCAN_B + threadIdx.x;
    int v = (i < n) ? degi[i] : 0;
    s[threadIdx.x] = v;
    __syncthreads();
    for (int off = 1; off < SCAN_B; off <<= 1) {
        int t = (threadIdx.x >= off) ? s[threadIdx.x - off] : 0;
        __syncthreads();
        if (threadIdx.x >= off) s[threadIdx.x] += t;
        __syncthreads();
    }
    // s now holds inclusive scan
    if (i < n) rowptr[i] = (threadIdx.x == 0) ? 0 : s[threadIdx.x - 1];
    if (threadIdx.x == 0) bsum[blockIdx.x] = s[SCAN_B - 1];
}

// Single-block exclusive scan of block sums.
__global__ __launch_bounds__(SCAN_B) void scan2_kernel(
    const int* __restrict__ bsum, int* __restrict__ boff, int nb)
{
    __shared__ int s[SCAN_B];
    int v = (threadIdx.x < nb) ? bsum[threadIdx.x] : 0;
    s[threadIdx.x] = v;
    __syncthreads();
    for (int off = 1; off < SCAN_B; off <<= 1) {
        int t = (threadIdx.x >= off) ? s[threadIdx.x - off] : 0;
        __syncthreads();
        if (threadIdx.x >= off) s[threadIdx.x] += t;
        __syncthreads();
    }
    if (threadIdx.x < nb)
        boff[threadIdx.x] = (threadIdx.x == 0) ? 0 : s[threadIdx.x - 1];
}

// Add block offsets; produce final rowptr and a working cursor copy.
__global__ __launch_bounds__(SCAN_B) void scan3_kernel(
    int* __restrict__ rowptr, int* __restrict__ cursor,
    const int* __restrict__ boff, int n, int E)
{
    int i = blockIdx.x * SCAN_B + threadIdx.x;
    if (i < n) {
        int r = rowptr[i] + boff[blockIdx.x];
        rowptr[i] = r;
        cursor[i] = r;
    }
    if (i == 0) rowptr[n] = E;
}

__global__ __launch_bounds__(256) void fill_kernel(
    const int* __restrict__ src, const int* __restrict__ dst,
    int* __restrict__ cursor, int* __restrict__ colidx, int E)
{
    int e = blockIdx.x * 256 + threadIdx.x;
    if (e >= E) return;
    int s = src[e];
    int d = dst[e];
    if ((unsigned)s >= (unsigned)N_NODES || (unsigned)d >= (unsigned)N_NODES) return;
    int pos = atomicAdd(&cursor[d], 1);
    colidx[pos] = s;
}

// ---------------------------------------------------------------------------
// CSR mean-aggregate: 32 lanes per node (float4 each over 128 ch), 8 nodes
// per 256-thread block. ACCUM: out += mean (layer 2); else out = mean.
// ---------------------------------------------------------------------------
template <bool ACCUM>
__global__ __launch_bounds__(256) void aggregate_kernel(
    const float* __restrict__ feat, const int* __restrict__ rowptr,
    const int* __restrict__ colidx, float* __restrict__ outp)
{
    const int g    = threadIdx.x >> 5;
    const int lane = threadIdx.x & 31;
    const int node = blockIdx.x * 8 + g;
    if (node >= N_NODES) return;
    const int beg = rowptr[node];
    const int end = rowptr[node + 1];

    float4 acc0 = {0.f, 0.f, 0.f, 0.f};
    float4 acc1 = {0.f, 0.f, 0.f, 0.f};
    int i = beg;
    for (; i + 1 < end; i += 2) {
        int s0 = colidx[i];
        int s1 = colidx[i + 1];
        const float4 v0 = *reinterpret_cast<const float4*>(feat + (size_t)s0 * 128 + lane * 4);
        const float4 v1 = *reinterpret_cast<const float4*>(feat + (size_t)s1 * 128 + lane * 4);
        acc0.x += v0.x; acc0.y += v0.y; acc0.z += v0.z; acc0.w += v0.w;
        acc1.x += v1.x; acc1.y += v1.y; acc1.z += v1.z; acc1.w += v1.w;
    }
    if (i < end) {
        int s0 = colidx[i];
        const float4 v0 = *reinterpret_cast<const float4*>(feat + (size_t)s0 * 128 + lane * 4);
        acc0.x += v0.x; acc0.y += v0.y; acc0.z += v0.z; acc0.w += v0.w;
    }
    const float sc = 1.0f / fmaxf((float)(end - beg), 1.0f);
    float4 r;
    r.x = (acc0.x + acc1.x) * sc;
    r.y = (acc0.y + acc1.y) * sc;
    r.z = (acc0.z + acc1.z) * sc;
    r.w = (acc0.w + acc1.w) * sc;

    float* o = outp + (size_t)node * 128 + lane * 4;
    if (ACCUM) {
        float4 t = *reinterpret_cast<float4*>(o);
        r.x += t.x; r.y += t.y; r.z += t.z; r.w += t.w;
    }
    *reinterpret_cast<float4*>(o) = r;
}

// ---------------------------------------------------------------------------
// Load a 64x32 tile of row-major [rows][K] matrix g into LDS transposed as
// s[kk][r]. 256 threads, 2 float4 global loads each.
// ---------------------------------------------------------------------------
__device__ __forceinline__ void load_tile_T(
    const float* __restrict__ g, float* __restrict__ s,
    int K, int rowBase, int kBase, int maxRow, int tid)
{
#pragma unroll
    for (int it = 0; it < 2; ++it) {
        int idx = tid + it * 256;        // float4 index within tile (0..511)
        int r   = idx >> 3;              // tile row 0..63
        int c4  = (idx & 7) << 2;        // k offset 0..28
        int row = rowBase + r;
        if (row >= maxRow) row = maxRow - 1;   // clamp; stores guarded at epilogue
        const float4 v = *reinterpret_cast<const float4*>(g + (size_t)row * K + kBase + c4);
        float* p0 = s + (size_t)c4 * LDT + r;
        p0[0 * LDT] = v.x;
        p0[1 * LDT] = v.y;
        p0[2 * LDT] = v.z;
        p0[3 * LDT] = v.w;
    }
}

// ---------------------------------------------------------------------------
// GEMM1: h = relu( mean1 @ W1l^T + b1l + x @ W1r^T )
// ---------------------------------------------------------------------------
__global__ __launch_bounds__(256) void gemm1_kernel(
    const float* __restrict__ mean1, const float* __restrict__ x,
    const float* __restrict__ W1l,   const float* __restrict__ W1r,
    const float* __restrict__ b1l,   float* __restrict__ h)
{
    __shared__ float As[TK][LDT];
    __shared__ float Bs[TK][LDT];

    const int tid = threadIdx.x;
    const int tx = tid & 15, ty = tid >> 4;
    const int rowBase = blockIdx.x * TM;
    const int colBase = blockIdx.y * TN;

    float acc[4][4] = {};

    for (int op = 0; op < 2; ++op) {
        const float* A = op ? x : mean1;
        const float* B = op ? W1r : W1l;
        for (int kb = 0; kb < IN_CH; kb += TK) {
            load_tile_T(A, &As[0][0], IN_CH, rowBase, kb, N_NODES, tid);
            load_tile_T(B, &Bs[0][0], IN_CH, colBase, kb, HID_CH, tid);
            __syncthreads();
#pragma unroll
            for (int kk = 0; kk < TK; ++kk) {
                float a[4], b[4];
                *reinterpret_cast<float4*>(a) = *reinterpret_cast<const float4*>(&As[kk][ty * 4]);
                *reinterpret_cast<float4*>(b) = *reinterpret_cast<const float4*>(&Bs[kk][tx * 4]);
#pragma unroll
                for (int i = 0; i < 4; ++i)
#pragma unroll
                    for (int j = 0; j < 4; ++j)
                        acc[i][j] = fmaf(a[i], b[j], acc[i][j]);
            }
            __syncthreads();
        }
    }

    float bias[4];
    *reinterpret_cast<float4*>(bias) = *reinterpret_cast<const float4*>(b1l + colBase + tx * 4);
#pragma unroll
    for (int i = 0; i < 4; ++i) {
        int row = rowBase + ty * 4 + i;
        if (row < N_NODES) {
            float4 o;
            o.x = fmaxf(acc[i][0] + bias[0], 0.0f);
            o.y = fmaxf(acc[i][1] + bias[1], 0.0f);
            o.z = fmaxf(acc[i][2] + bias[2], 0.0f);
            o.w = fmaxf(acc[i][3] + bias[3], 0.0f);
            *reinterpret_cast<float4*>(h + (size_t)row * HID_CH + colBase + tx * 4) = o;
        }
    }
}

// ---------------------------------------------------------------------------
// GEMM2 (fused): p = h @ W2l^T ; out = h @ W2r^T + b2l
// ---------------------------------------------------------------------------
__global__ __launch_bounds__(256) void gemm2_kernel(
    const float* __restrict__ h,   const float* __restrict__ W2l,
    const float* __restrict__ W2r, const float* __restrict__ b2l,
    float* __restrict__ p, float* __restrict__ out)
{
    __shared__ float As[TK][LDT];
    __shared__ float Bl[TK][LDT];
    __shared__ float Br[TK][LDT];

    const int tid = threadIdx.x;
    const int tx = tid & 15, ty = tid >> 4;
    const int rowBase = blockIdx.x * TM;
    const int colBase = blockIdx.y * TN;

    float accl[4][4] = {};
    float accr[4][4] = {};

    for (int kb = 0; kb < HID_CH; kb += TK) {
        load_tile_T(h,   &As[0][0], HID_CH, rowBase, kb, N_NODES, tid);
        load_tile_T(W2l, &Bl[0][0], HID_CH, colBase, kb, OUT_CH, tid);
        load_tile_T(W2r, &Br[0][0], HID_CH, colBase, kb, OUT_CH, tid);
        __syncthreads();
#pragma unroll
        for (int kk = 0; kk < TK; ++kk) {
            float a[4], bl[4], br[4];
            *reinterpret_cast<float4*>(a)  = *reinterpret_cast<const float4*>(&As[kk][ty * 4]);
            *reinterpret_cast<float4*>(bl) = *reinterpret_cast<const float4*>(&Bl[kk][tx * 4]);
            *reinterpret_cast<float4*>(br) = *reinterpret_cast<const float4*>(&Br[kk][tx * 4]);
#pragma unroll
            for (int i = 0; i < 4; ++i)
#pragma unroll
                for (int j = 0; j < 4; ++j) {
                    accl[i][j] = fmaf(a[i], bl[j], accl[i][j]);
                    accr[i][j] = fmaf(a[i], br[j], accr[i][j]);
                }
        }
        __syncthreads();
    }

    float bias[4];
    *reinterpret_cast<float4*>(bias) = *reinterpret_cast<const float4*>(b2l + colBase + tx * 4);
#pragma unroll
    for (int i = 0; i < 4; ++i) {
        int row = rowBase + ty * 4 + i;
        if (row < N_NODES) {
            *reinterpret_cast<float4*>(p + (size_t)row * OUT_CH + colBase + tx * 4) =
                *reinterpret_cast<float4*>(accl[i]);
            float4 o;
            o.x = accr[i][0] + bias[0];
            o.y = accr[i][1] + bias[1];
            o.z = accr[i][2] + bias[2];
            o.w = accr[i][3] + bias[3];
            *reinterpret_cast<float4*>(out + (size_t)row * OUT_CH + colBase + tx * 4) = o;
        }
    }
}

extern "C" void kernel_launch(void* const* d_in, const int* in_sizes, int n_in,
                              void* d_out, int out_size, void* d_ws, size_t ws_size,
                              hipStream_t stream)
{
    const float* x   = (const float*)d_in[0];
    const int*   ei  = (const int*)d_in[1];
    const float* W1l = (const float*)d_in[2];
    const float* b1l = (const float*)d_in[3];
    const float* W1r = (const float*)d_in[4];
    const float* W2l = (const float*)d_in[5];
    const float* b2l = (const float*)d_in[6];
    const float* W2r = (const float*)d_in[7];

    const int E = in_sizes[1] / 2;
    const int* src = ei;
    const int* dst = ei + E;

    // Workspace layout
    char* ws = (char*)d_ws;
    size_t off = 0;
    float* mean1  = (float*)(ws + off); off += (size_t)N_NODES * IN_CH  * 4;  // 25.6 MB
    float* h      = (float*)(ws + off); off += (size_t)N_NODES * HID_CH * 4;  // 51.2 MB
    int*   degi   = (int*)(ws + off);   off += (size_t)N_NODES * 4;
    int*   rowptr = (int*)(ws + off);   off += (size_t)(N_NODES + 1) * 4;
    int*   cursor = (int*)(ws + off);   off += (size_t)N_NODES * 4;
    int*   bsum   = (int*)(ws + off);   off += (size_t)SCAN_B * 4;
    int*   boff   = (int*)(ws + off);   off += (size_t)SCAN_B * 4;
    int*   colidx = (int*)(ws + off);   off += (size_t)E * 4;                  // 3.2 MB
    float* p   = mean1;      // mean1 dead after gemm1
    float* out = (float*)d_out;

    const int nb = (N_NODES + SCAN_B - 1) / SCAN_B;   // 196 <= SCAN_B

    // CSR build (by dst)
    hipMemsetAsync(degi, 0, (size_t)N_NODES * 4, stream);
    hist_kernel<<<(E + 255) / 256, 256, 0, stream>>>(dst, degi, E);
    scan1_kernel<<<nb, SCAN_B, 0, stream>>>(degi, rowptr, bsum, N_NODES);
    scan2_kernel<<<1, SCAN_B, 0, stream>>>(bsum, boff, nb);
    scan3_kernel<<<nb, SCAN_B, 0, stream>>>(rowptr, cursor, boff, N_NODES, E);
    fill_kernel<<<(E + 255) / 256, 256, 0, stream>>>(src, dst, cursor, colidx, E);

    const int aggBlocks = (N_NODES + 7) / 8;

    // Layer 1: mean-aggregate x, then fused GEMM (+bias, +relu)
    aggregate_kernel<false><<<aggBlocks, 256, 0, stream>>>(x, rowptr, colidx, mean1);
    gemm1_kernel<<<dim3((N_NODES + TM - 1) / TM, HID_CH / TN), 256, 0, stream>>>(
        mean1, x, W1l, W1r, b1l, h);

    // Layer 2: transform-then-aggregate (mean(h)@W2l^T == mean(h@W2l^T))
    gemm2_kernel<<<dim3((N_NODES + TM - 1) / TM, OUT_CH / TN), 256, 0, stream>>>(
        h, W2l, W2r, b2l, p, out);
    aggregate_kernel<true><<<aggBlocks, 256, 0, stream>>>(p, rowptr, colidx, out);
}

// Round 3
// 312.279 us; speedup vs baseline: 9.6850x; 1.5250x over previous
//
#include <hip/hip_runtime.h>

#define N_NODES 50000
#define IN_CH   128
#define HID_CH  256
#define OUT_CH  128
#define SCAN_B  256

#define LSTR 72   // LDS row stride in bf16 elems: 64 K + 8 pad -> 2-way bank aliasing (free)

typedef __attribute__((ext_vector_type(8))) short bf16x8;
typedef __attribute__((ext_vector_type(4))) float f32x4;

__device__ __forceinline__ unsigned short f32_bf16_rne(float f) {
    unsigned u = __float_as_uint(f);
    unsigned r = u + 0x7fff + ((u >> 16) & 1);
    return (unsigned short)(r >> 16);
}
__device__ __forceinline__ float bf16lo_f32(unsigned u) { return __uint_as_float(u << 16); }
__device__ __forceinline__ float bf16hi_f32(unsigned u) { return __uint_as_float(u & 0xffff0000u); }

// ---------------------------------------------------------------------------
// fp32 -> bf16 conversion, 8 elements per thread (n must be divisible by 8)
// ---------------------------------------------------------------------------
__global__ __launch_bounds__(256) void cvt_bf16_kernel(
    const float* __restrict__ in, unsigned short* __restrict__ outp, int n8)
{
    int i = blockIdx.x * 256 + threadIdx.x;
    if (i >= n8) return;
    const float4* p = reinterpret_cast<const float4*>(in) + 2 * (size_t)i;
    float4 a = p[0], b = p[1];
    alignas(16) unsigned short t[8] = {
        f32_bf16_rne(a.x), f32_bf16_rne(a.y), f32_bf16_rne(a.z), f32_bf16_rne(a.w),
        f32_bf16_rne(b.x), f32_bf16_rne(b.y), f32_bf16_rne(b.z), f32_bf16_rne(b.w)};
    *reinterpret_cast<int4*>(outp + 8 * (size_t)i) = *reinterpret_cast<const int4*>(t);
}

// ---------------------------------------------------------------------------
// CSR build: histogram of dst, exclusive scan -> rowptr, cursor fill -> colidx
// ---------------------------------------------------------------------------
__global__ __launch_bounds__(256) void hist_kernel(
    const int* __restrict__ dst, int* __restrict__ degi, int E)
{
    int e = blockIdx.x * 256 + threadIdx.x;
    if (e >= E) return;
    int d = dst[e];
    if ((unsigned)d < (unsigned)N_NODES) atomicAdd(&degi[d], 1);
}

__global__ __launch_bounds__(SCAN_B) void scan1_kernel(
    const int* __restrict__ degi, int* __restrict__ rowptr,
    int* __restrict__ bsum, int n)
{
    __shared__ int s[SCAN_B];
    int i = blockIdx.x * SCAN_B + threadIdx.x;
    int v = (i < n) ? degi[i] : 0;
    s[threadIdx.x] = v;
    __syncthreads();
    for (int off = 1; off < SCAN_B; off <<= 1) {
        int t = (threadIdx.x >= off) ? s[threadIdx.x - off] : 0;
        __syncthreads();
        if (threadIdx.x >= off) s[threadIdx.x] += t;
        __syncthreads();
    }
    if (i < n) rowptr[i] = (threadIdx.x == 0) ? 0 : s[threadIdx.x - 1];
    if (threadIdx.x == 0) bsum[blockIdx.x] = s[SCAN_B - 1];
}

__global__ __launch_bounds__(SCAN_B) void scan2_kernel(
    const int* __restrict__ bsum, int* __restrict__ boff, int nb)
{
    __shared__ int s[SCAN_B];
    int v = (threadIdx.x < nb) ? bsum[threadIdx.x] : 0;
    s[threadIdx.x] = v;
    __syncthreads();
    for (int off = 1; off < SCAN_B; off <<= 1) {
        int t = (threadIdx.x >= off) ? s[threadIdx.x - off] : 0;
        __syncthreads();
        if (threadIdx.x >= off) s[threadIdx.x] += t;
        __syncthreads();
    }
    if (threadIdx.x < nb)
        boff[threadIdx.x] = (threadIdx.x == 0) ? 0 : s[threadIdx.x - 1];
}

__global__ __launch_bounds__(SCAN_B) void scan3_kernel(
    int* __restrict__ rowptr, int* __restrict__ cursor,
    const int* __restrict__ boff, int n, int E)
{
    int i = blockIdx.x * SCAN_B + threadIdx.x;
    if (i < n) {
        int r = rowptr[i] + boff[blockIdx.x];
        rowptr[i] = r;
        cursor[i] = r;
    }
    if (i == 0) rowptr[n] = E;
}

__global__ __launch_bounds__(256) void fill_kernel(
    const int* __restrict__ src, const int* __restrict__ dst,
    int* __restrict__ cursor, int* __restrict__ colidx, int E)
{
    int e = blockIdx.x * 256 + threadIdx.x;
    if (e >= E) return;
    int s = src[e];
    int d = dst[e];
    if ((unsigned)s >= (unsigned)N_NODES || (unsigned)d >= (unsigned)N_NODES) return;
    int pos = atomicAdd(&cursor[d], 1);
    colidx[pos] = s;
}

// ---------------------------------------------------------------------------
// Layer-1 aggregate: mean over bf16 neighbor rows (128ch), fp32 accum,
// bf16 out. 16 lanes per node (16B each), 16 nodes per 256-thread block.
// ---------------------------------------------------------------------------
__global__ __launch_bounds__(256) void agg1_kernel(
    const unsigned short* __restrict__ feat, const int* __restrict__ rowptr,
    const int* __restrict__ colidx, unsigned short* __restrict__ outp)
{
    const int node = blockIdx.x * 16 + (threadIdx.x >> 4);
    const int lane = threadIdx.x & 15;
    if (node >= N_NODES) return;
    const int beg = rowptr[node];
    const int end = rowptr[node + 1];

    float acc[8] = {};
    int i = beg;
    for (; i + 1 < end; i += 2) {
        int s0 = colidx[i], s1 = colidx[i + 1];
        int4 v0 = *reinterpret_cast<const int4*>(feat + (size_t)s0 * IN_CH + lane * 8);
        int4 v1 = *reinterpret_cast<const int4*>(feat + (size_t)s1 * IN_CH + lane * 8);
        acc[0] += bf16lo_f32(v0.x); acc[1] += bf16hi_f32(v0.x);
        acc[2] += bf16lo_f32(v0.y); acc[3] += bf16hi_f32(v0.y);
        acc[4] += bf16lo_f32(v0.z); acc[5] += bf16hi_f32(v0.z);
        acc[6] += bf16lo_f32(v0.w); acc[7] += bf16hi_f32(v0.w);
        acc[0] += bf16lo_f32(v1.x); acc[1] += bf16hi_f32(v1.x);
        acc[2] += bf16lo_f32(v1.y); acc[3] += bf16hi_f32(v1.y);
        acc[4] += bf16lo_f32(v1.z); acc[5] += bf16hi_f32(v1.z);
        acc[6] += bf16lo_f32(v1.w); acc[7] += bf16hi_f32(v1.w);
    }
    if (i < end) {
        int s0 = colidx[i];
        int4 v0 = *reinterpret_cast<const int4*>(feat + (size_t)s0 * IN_CH + lane * 8);
        acc[0] += bf16lo_f32(v0.x); acc[1] += bf16hi_f32(v0.x);
        acc[2] += bf16lo_f32(v0.y); acc[3] += bf16hi_f32(v0.y);
        acc[4] += bf16lo_f32(v0.z); acc[5] += bf16hi_f32(v0.z);
        acc[6] += bf16lo_f32(v0.w); acc[7] += bf16hi_f32(v0.w);
    }
    const float sc = 1.0f / fmaxf((float)(end - beg), 1.0f);
    alignas(16) unsigned short t[8];
#pragma unroll
    for (int j = 0; j < 8; ++j) t[j] = f32_bf16_rne(acc[j] * sc);
    *reinterpret_cast<int4*>(outp + (size_t)node * IN_CH + lane * 8) =
        *reinterpret_cast<const int4*>(t);
}

// ---------------------------------------------------------------------------
// Layer-2 aggregate: out(f32) += mean over bf16 rows of p (128ch).
// ---------------------------------------------------------------------------
__global__ __launch_bounds__(256) void agg2_kernel(
    const unsigned short* __restrict__ feat, const int* __restrict__ rowptr,
    const int* __restrict__ colidx, float* __restrict__ out)
{
    const int node = blockIdx.x * 16 + (threadIdx.x >> 4);
    const int lane = threadIdx.x & 15;
    if (node >= N_NODES) return;
    const int beg = rowptr[node];
    const int end = rowptr[node + 1];

    float acc[8] = {};
    int i = beg;
    for (; i + 1 < end; i += 2) {
        int s0 = colidx[i], s1 = colidx[i + 1];
        int4 v0 = *reinterpret_cast<const int4*>(feat + (size_t)s0 * OUT_CH + lane * 8);
        int4 v1 = *reinterpret_cast<const int4*>(feat + (size_t)s1 * OUT_CH + lane * 8);
        acc[0] += bf16lo_f32(v0.x); acc[1] += bf16hi_f32(v0.x);
        acc[2] += bf16lo_f32(v0.y); acc[3] += bf16hi_f32(v0.y);
        acc[4] += bf16lo_f32(v0.z); acc[5] += bf16hi_f32(v0.z);
        acc[6] += bf16lo_f32(v0.w); acc[7] += bf16hi_f32(v0.w);
        acc[0] += bf16lo_f32(v1.x); acc[1] += bf16hi_f32(v1.x);
        acc[2] += bf16lo_f32(v1.y); acc[3] += bf16hi_f32(v1.y);
        acc[4] += bf16lo_f32(v1.z); acc[5] += bf16hi_f32(v1.z);
        acc[6] += bf16lo_f32(v1.w); acc[7] += bf16hi_f32(v1.w);
    }
    if (i < end) {
        int s0 = colidx[i];
        int4 v0 = *reinterpret_cast<const int4*>(feat + (size_t)s0 * OUT_CH + lane * 8);
        acc[0] += bf16lo_f32(v0.x); acc[1] += bf16hi_f32(v0.x);
        acc[2] += bf16lo_f32(v0.y); acc[3] += bf16hi_f32(v0.y);
        acc[4] += bf16lo_f32(v0.z); acc[5] += bf16hi_f32(v0.z);
        acc[6] += bf16lo_f32(v0.w); acc[7] += bf16hi_f32(v0.w);
    }
    const float sc = 1.0f / fmaxf((float)(end - beg), 1.0f);
    float* o = out + (size_t)node * OUT_CH + lane * 8;
    float4 o0 = reinterpret_cast<float4*>(o)[0];
    float4 o1 = reinterpret_cast<float4*>(o)[1];
    o0.x += acc[0] * sc; o0.y += acc[1] * sc; o0.z += acc[2] * sc; o0.w += acc[3] * sc;
    o1.x += acc[4] * sc; o1.y += acc[5] * sc; o1.z += acc[6] * sc; o1.w += acc[7] * sc;
    reinterpret_cast<float4*>(o)[0] = o0;
    reinterpret_cast<float4*>(o)[1] = o1;
}

// ---------------------------------------------------------------------------
// MFMA GEMM pieces. Block = 256 threads = 4 waves (2x2), block tile 128x128,
// wave tile 64x64 (4x4 subtiles of 16x16), mfma_f32_16x16x32_bf16.
// A [M][K] bf16 row-major, B [N][K] bf16 row-major: C[m][n] = sum_k A*B.
// Frag layout (both operands): lane holds row (lane&15), k = (lane>>4)*8 + j.
// C/D: col = lane&15, row = (lane>>4)*4 + reg.
// ---------------------------------------------------------------------------
__device__ __forceinline__ void stage64(
    const unsigned short* __restrict__ g, int ldg, int rowBase, int maxRow,
    int kBase, unsigned short* __restrict__ s, int tid)
{
    // 128 rows x 64 k bf16 = 1024 16B chunks; 4 per thread
#pragma unroll
    for (int it = 0; it < 4; ++it) {
        int c = tid + it * 256;
        int r = c >> 3;              // 0..127
        int off = (c & 7) * 8;       // 0..56 bf16
        int row = rowBase + r;
        if (row >= maxRow) row = maxRow - 1;   // clamp; epilogue guards stores
        int4 v = *reinterpret_cast<const int4*>(g + (size_t)row * ldg + kBase + off);
        *reinterpret_cast<int4*>(s + r * LSTR + off) = v;
    }
}

__device__ __forceinline__ void mfma_tile(
    const unsigned short* __restrict__ As, const unsigned short* __restrict__ Bs,
    int wm, int wn, int l16, int quad, f32x4 acc[4][4])
{
#pragma unroll
    for (int k0 = 0; k0 < 64; k0 += 32) {
        bf16x8 a[4], b[4];
#pragma unroll
        for (int i = 0; i < 4; ++i)
            a[i] = *reinterpret_cast<const bf16x8*>(
                As + (wm * 64 + i * 16 + l16) * LSTR + k0 + quad * 8);
#pragma unroll
        for (int j = 0; j < 4; ++j)
            b[j] = *reinterpret_cast<const bf16x8*>(
                Bs + (wn * 64 + j * 16 + l16) * LSTR + k0 + quad * 8);
#pragma unroll
        for (int i = 0; i < 4; ++i)
#pragma unroll
            for (int j = 0; j < 4; ++j)
                acc[i][j] = __builtin_amdgcn_mfma_f32_16x16x32_bf16(
                    a[i], b[j], acc[i][j], 0, 0, 0);
    }
}

// GEMM1: h = relu(mean1b @ W1l^T + b1l + xb @ W1r^T), bf16 out [M][256]
__global__ __launch_bounds__(256) void gemm1_mfma(
    const unsigned short* __restrict__ mean1b, const unsigned short* __restrict__ xb,
    const unsigned short* __restrict__ W1lb,   const unsigned short* __restrict__ W1rb,
    const float* __restrict__ b1l, unsigned short* __restrict__ hb)
{
    __shared__ unsigned short As[128 * LSTR];
    __shared__ unsigned short Bs[128 * LSTR];
    const int tid = threadIdx.x;
    const int wid = tid >> 6, lane = tid & 63;
    const int wm = wid & 1, wn = wid >> 1;
    const int l16 = lane & 15, quad = lane >> 4;
    const int rowBase = blockIdx.x * 128;
    const int colBase = blockIdx.y * 128;

    f32x4 z = {0.f, 0.f, 0.f, 0.f};
    f32x4 acc[4][4];
#pragma unroll
    for (int i = 0; i < 4; ++i)
#pragma unroll
        for (int j = 0; j < 4; ++j) acc[i][j] = z;

#pragma unroll
    for (int op = 0; op < 2; ++op) {
        const unsigned short* A = op ? xb : mean1b;
        const unsigned short* B = op ? W1rb : W1lb;
#pragma unroll
        for (int kb = 0; kb < IN_CH; kb += 64) {
            __syncthreads();
            stage64(A, IN_CH, rowBase, N_NODES, kb, As, tid);
            stage64(B, IN_CH, colBase, HID_CH, kb, Bs, tid);
            __syncthreads();
            mfma_tile(As, Bs, wm, wn, l16, quad, acc);
        }
    }

#pragma unroll
    for (int j = 0; j < 4; ++j) {
        int col = colBase + wn * 64 + j * 16 + l16;
        float bv = b1l[col];
#pragma unroll
        for (int i = 0; i < 4; ++i) {
            int mBase = rowBase + wm * 64 + i * 16 + quad * 4;
#pragma unroll
            for (int r = 0; r < 4; ++r) {
                int m = mBase + r;
                if (m < N_NODES) {
                    float v = fmaxf(acc[i][j][r] + bv, 0.0f);
                    hb[(size_t)m * HID_CH + col] = f32_bf16_rne(v);
                }
            }
        }
    }
}

// GEMM2: blockIdx.y==0 -> p = h @ W2l^T (bf16, no bias)
//        blockIdx.y==1 -> out = h @ W2r^T + b2l (f32)
__global__ __launch_bounds__(256) void gemm2_mfma(
    const unsigned short* __restrict__ hb, const unsigned short* __restrict__ W2lb,
    const unsigned short* __restrict__ W2rb, const float* __restrict__ b2l,
    unsigned short* __restrict__ pb, float* __restrict__ out)
{
    __shared__ unsigned short As[128 * LSTR];
    __shared__ unsigned short Bs[128 * LSTR];
    const int tid = threadIdx.x;
    const int wid = tid >> 6, lane = tid & 63;
    const int wm = wid & 1, wn = wid >> 1;
    const int l16 = lane & 15, quad = lane >> 4;
    const int rowBase = blockIdx.x * 128;
    const unsigned short* B = blockIdx.y ? W2rb : W2lb;

    f32x4 z = {0.f, 0.f, 0.f, 0.f};
    f32x4 acc[4][4];
#pragma unroll
    for (int i = 0; i < 4; ++i)
#pragma unroll
        for (int j = 0; j < 4; ++j) acc[i][j] = z;

#pragma unroll
    for (int kb = 0; kb < HID_CH; kb += 64) {
        __syncthreads();
        stage64(hb, HID_CH, rowBase, N_NODES, kb, As, tid);
        stage64(B, HID_CH, 0, OUT_CH, kb, Bs, tid);
        __syncthreads();
        mfma_tile(As, Bs, wm, wn, l16, quad, acc);
    }

    if (blockIdx.y == 0) {
#pragma unroll
        for (int j = 0; j < 4; ++j) {
            int col = wn * 64 + j * 16 + l16;
#pragma unroll
            for (int i = 0; i < 4; ++i) {
                int mBase = rowBase + wm * 64 + i * 16 + quad * 4;
#pragma unroll
                for (int r = 0; r < 4; ++r) {
                    int m = mBase + r;
                    if (m < N_NODES)
                        pb[(size_t)m * OUT_CH + col] = f32_bf16_rne(acc[i][j][r]);
                }
            }
        }
    } else {
#pragma unroll
        for (int j = 0; j < 4; ++j) {
            int col = wn * 64 + j * 16 + l16;
            float bv = b2l[col];
#pragma unroll
            for (int i = 0; i < 4; ++i) {
                int mBase = rowBase + wm * 64 + i * 16 + quad * 4;
#pragma unroll
                for (int r = 0; r < 4; ++r) {
                    int m = mBase + r;
                    if (m < N_NODES)
                        out[(size_t)m * OUT_CH + col] = acc[i][j][r] + bv;
                }
            }
        }
    }
}

extern "C" void kernel_launch(void* const* d_in, const int* in_sizes, int n_in,
                              void* d_out, int out_size, void* d_ws, size_t ws_size,
                              hipStream_t stream)
{
    const float* x   = (const float*)d_in[0];
    const int*   ei  = (const int*)d_in[1];
    const float* W1l = (const float*)d_in[2];
    const float* b1l = (const float*)d_in[3];
    const float* W1r = (const float*)d_in[4];
    const float* W2l = (const float*)d_in[5];
    const float* b2l = (const float*)d_in[6];
    const float* W2r = (const float*)d_in[7];

    const int E = in_sizes[1] / 2;
    const int* src = ei;
    const int* dst = ei + E;

    char* ws = (char*)d_ws;
    size_t off = 0;
    auto alloc = [&](size_t bytes) {
        void* p = ws + off;
        off += (bytes + 255) & ~(size_t)255;
        return p;
    };
    unsigned short* xb     = (unsigned short*)alloc((size_t)N_NODES * IN_CH * 2);
    unsigned short* mean1b = (unsigned short*)alloc((size_t)N_NODES * IN_CH * 2);
    unsigned short* hb     = (unsigned short*)alloc((size_t)N_NODES * HID_CH * 2);
    unsigned short* pb     = (unsigned short*)alloc((size_t)N_NODES * OUT_CH * 2);
    unsigned short* W1lb   = (unsigned short*)alloc((size_t)HID_CH * IN_CH * 2);
    unsigned short* W1rb   = (unsigned short*)alloc((size_t)HID_CH * IN_CH * 2);
    unsigned short* W2lb   = (unsigned short*)alloc((size_t)OUT_CH * HID_CH * 2);
    unsigned short* W2rb   = (unsigned short*)alloc((size_t)OUT_CH * HID_CH * 2);
    int* degi   = (int*)alloc((size_t)N_NODES * 4);
    int* rowptr = (int*)alloc((size_t)(N_NODES + 1) * 4);
    int* cursor = (int*)alloc((size_t)N_NODES * 4);
    int* bsum   = (int*)alloc((size_t)SCAN_B * 4);
    int* boff   = (int*)alloc((size_t)SCAN_B * 4);
    int* colidx = (int*)alloc((size_t)E * 4);
    float* out = (float*)d_out;

    const int nb = (N_NODES + SCAN_B - 1) / SCAN_B;   // 196 <= SCAN_B

    // CSR build (by dst)
    hipMemsetAsync(degi, 0, (size_t)N_NODES * 4, stream);
    hist_kernel<<<(E + 255) / 256, 256, 0, stream>>>(dst, degi, E);
    scan1_kernel<<<nb, SCAN_B, 0, stream>>>(degi, rowptr, bsum, N_NODES);
    scan2_kernel<<<1, SCAN_B, 0, stream>>>(bsum, boff, nb);
    scan3_kernel<<<nb, SCAN_B, 0, stream>>>(rowptr, cursor, boff, N_NODES, E);
    fill_kernel<<<(E + 255) / 256, 256, 0, stream>>>(src, dst, cursor, colidx, E);

    // bf16 conversions
    const int xn8 = N_NODES * IN_CH / 8;
    cvt_bf16_kernel<<<(xn8 + 255) / 256, 256, 0, stream>>>(x, xb, xn8);
    const int wn8 = HID_CH * IN_CH / 8;   // 4096 (same size for all 4 weights)
    cvt_bf16_kernel<<<(wn8 + 255) / 256, 256, 0, stream>>>(W1l, W1lb, wn8);
    cvt_bf16_kernel<<<(wn8 + 255) / 256, 256, 0, stream>>>(W1r, W1rb, wn8);
    cvt_bf16_kernel<<<(wn8 + 255) / 256, 256, 0, stream>>>(W2l, W2lb, wn8);
    cvt_bf16_kernel<<<(wn8 + 255) / 256, 256, 0, stream>>>(W2r, W2rb, wn8);

    const int aggBlocks = (N_NODES + 15) / 16;
    const int mBlocks = (N_NODES + 127) / 128;   // 391

    // Layer 1
    agg1_kernel<<<aggBlocks, 256, 0, stream>>>(xb, rowptr, colidx, mean1b);
    gemm1_mfma<<<dim3(mBlocks, HID_CH / 128), 256, 0, stream>>>(
        mean1b, xb, W1lb, W1rb, b1l, hb);

    // Layer 2 (transform-then-aggregate)
    gemm2_mfma<<<dim3(mBlocks, 2), 256, 0, stream>>>(hb, W2lb, W2rb, b2l, pb, out);
    agg2_kernel<<<aggBlocks, 256, 0, stream>>>(pb, rowptr, colidx, out);
}

// Round 4
// 260.948 us; speedup vs baseline: 11.5901x; 1.1967x over previous
//
#include <hip/hip_runtime.h>

#define N_NODES 50000
#define IN_CH   128
#define HID_CH  256
#define OUT_CH  128

#define NB    196      // buckets: dst>>8, 50000>>8 = 195 -> 196 buckets
#define NWG   64       // phase-1 workgroups
#define NBNW  (NB * NWG)   // 12544 = 49 * 256 exactly

#define LSTR 72   // LDS row stride in bf16 elems: 64 K + 8 pad -> 2-way bank aliasing (free)

typedef __attribute__((ext_vector_type(8))) short bf16x8;
typedef __attribute__((ext_vector_type(4))) float f32x4;

__device__ __forceinline__ unsigned short f32_bf16_rne(float f) {
    unsigned u = __float_as_uint(f);
    unsigned r = u + 0x7fff + ((u >> 16) & 1);
    return (unsigned short)(r >> 16);
}
__device__ __forceinline__ float bf16lo_f32(unsigned u) { return __uint_as_float(u << 16); }
__device__ __forceinline__ float bf16hi_f32(unsigned u) { return __uint_as_float(u & 0xffff0000u); }

// ---------------------------------------------------------------------------
// fp32 -> bf16, 8 elements/thread
// ---------------------------------------------------------------------------
__global__ __launch_bounds__(256) void cvt_bf16_kernel(
    const float* __restrict__ in, unsigned short* __restrict__ outp, int n8)
{
    int i = blockIdx.x * 256 + threadIdx.x;
    if (i >= n8) return;
    const float4* p = reinterpret_cast<const float4*>(in) + 2 * (size_t)i;
    float4 a = p[0], b = p[1];
    alignas(16) unsigned short t[8] = {
        f32_bf16_rne(a.x), f32_bf16_rne(a.y), f32_bf16_rne(a.z), f32_bf16_rne(a.w),
        f32_bf16_rne(b.x), f32_bf16_rne(b.y), f32_bf16_rne(b.z), f32_bf16_rne(b.w)};
    *reinterpret_cast<int4*>(outp + 8 * (size_t)i) = *reinterpret_cast<const int4*>(t);
}

// All 4 weight matrices in one launch; per = n8 groups per matrix (4096)
__global__ __launch_bounds__(256) void cvt4_bf16_kernel(
    const float* __restrict__ a0, const float* __restrict__ a1,
    const float* __restrict__ a2, const float* __restrict__ a3,
    unsigned short* __restrict__ o0, unsigned short* __restrict__ o1,
    unsigned short* __restrict__ o2, unsigned short* __restrict__ o3, int per)
{
    int i = blockIdx.x * 256 + threadIdx.x;
    if (i >= 4 * per) return;
    int seg = i / per, j = i - seg * per;
    const float* in = (seg == 0) ? a0 : (seg == 1) ? a1 : (seg == 2) ? a2 : a3;
    unsigned short* outp = (seg == 0) ? o0 : (seg == 1) ? o1 : (seg == 2) ? o2 : o3;
    const float4* p = reinterpret_cast<const float4*>(in) + 2 * (size_t)j;
    float4 a = p[0], b = p[1];
    alignas(16) unsigned short t[8] = {
        f32_bf16_rne(a.x), f32_bf16_rne(a.y), f32_bf16_rne(a.z), f32_bf16_rne(a.w),
        f32_bf16_rne(b.x), f32_bf16_rne(b.y), f32_bf16_rne(b.z), f32_bf16_rne(b.w)};
    *reinterpret_cast<int4*>(outp + 8 * (size_t)j) = *reinterpret_cast<const int4*>(t);
}

// ---------------------------------------------------------------------------
// CSR build, two-level counting sort with XCD-exclusive write regions.
// ---------------------------------------------------------------------------
// Phase 1a: per-(wg,bucket) counts, bucket-major layout counts[b*NWG + w]
__global__ __launch_bounds__(256) void bcount_kernel(
    const int* __restrict__ src, const int* __restrict__ dst,
    int* __restrict__ counts, int E, int chunk)
{
    __shared__ int h[NB];
    const int w = blockIdx.x;
    for (int i = threadIdx.x; i < NB; i += 256) h[i] = 0;
    __syncthreads();
    const int e0 = w * chunk;
    const int e1 = min(e0 + chunk, E);
    for (int e = e0 + threadIdx.x; e < e1; e += 256) {
        int s = src[e], d = dst[e];
        if ((unsigned)s < (unsigned)N_NODES && (unsigned)d < (unsigned)N_NODES)
            atomicAdd(&h[d >> 8], 1);
    }
    __syncthreads();
    for (int i = threadIdx.x; i < NB; i += 256)
        counts[i * NWG + w] = h[i];
}

// Exclusive scan of counts[NBNW] -> S (3 kernels, 49 blocks of 256)
__global__ __launch_bounds__(256) void scanA_kernel(
    const int* __restrict__ counts, int* __restrict__ S, int* __restrict__ bsum)
{
    __shared__ int s[256];
    int i = blockIdx.x * 256 + threadIdx.x;
    s[threadIdx.x] = (i < NBNW) ? counts[i] : 0;
    __syncthreads();
    for (int off = 1; off < 256; off <<= 1) {
        int t = (threadIdx.x >= off) ? s[threadIdx.x - off] : 0;
        __syncthreads();
        if (threadIdx.x >= off) s[threadIdx.x] += t;
        __syncthreads();
    }
    if (i < NBNW) S[i] = (threadIdx.x == 0) ? 0 : s[threadIdx.x - 1];
    if (threadIdx.x == 0) bsum[blockIdx.x] = s[255];
}

__global__ __launch_bounds__(256) void scanB_kernel(
    const int* __restrict__ bsum, int* __restrict__ boff, int nb)
{
    __shared__ int s[256];
    int v = (threadIdx.x < nb) ? bsum[threadIdx.x] : 0;
    s[threadIdx.x] = v;
    __syncthreads();
    for (int off = 1; off < 256; off <<= 1) {
        int t = (threadIdx.x >= off) ? s[threadIdx.x - off] : 0;
        __syncthreads();
        if (threadIdx.x >= off) s[threadIdx.x] += t;
        __syncthreads();
    }
    if (threadIdx.x < nb)
        boff[threadIdx.x] = (threadIdx.x == 0) ? 0 : s[threadIdx.x - 1];
}

__global__ __launch_bounds__(256) void scanC_kernel(
    int* __restrict__ S, const int* __restrict__ boff,
    const int* __restrict__ counts)
{
    int i = blockIdx.x * 256 + threadIdx.x;
    if (i < NBNW) {
        int r = S[i] + boff[blockIdx.x];
        S[i] = r;
        if (i == NBNW - 1) S[NBNW] = r + counts[i];   // total valid edges
    }
}

// Phase 1b: scatter (src,dst) pairs into (bucket,wg)-exclusive subregions.
__global__ __launch_bounds__(256) void bscatter_kernel(
    const int* __restrict__ src, const int* __restrict__ dst,
    const int* __restrict__ S, int2* __restrict__ pairs, int E, int chunk)
{
    __shared__ int cur[NB];
    const int w = blockIdx.x;
    for (int i = threadIdx.x; i < NB; i += 256) cur[i] = S[i * NWG + w];
    __syncthreads();
    const int e0 = w * chunk;
    const int e1 = min(e0 + chunk, E);
    for (int e = e0 + threadIdx.x; e < e1; e += 256) {
        int s = src[e], d = dst[e];
        if ((unsigned)s < (unsigned)N_NODES && (unsigned)d < (unsigned)N_NODES) {
            int pos = atomicAdd(&cur[d >> 8], 1);
            pairs[pos] = make_int2(s, d);
        }
    }
}

// Phase 2: per-bucket local counting sort -> rowptr + colidx (bucket-exclusive
// contiguous spans; all HBM writes ~fully-dirtied lines).
__global__ __launch_bounds__(256) void bsort_kernel(
    const int2* __restrict__ pairs, const int* __restrict__ S,
    int* __restrict__ rowptr, int* __restrict__ colidx)
{
    __shared__ int hcnt[256];
    __shared__ int hcur[256];
    const int b = blockIdx.x;
    const int start = S[b * NWG];
    const int endv  = (b == NB - 1) ? S[NBNW] : S[(b + 1) * NWG];

    hcnt[threadIdx.x] = 0;
    __syncthreads();
    for (int e = start + threadIdx.x; e < endv; e += 256)
        atomicAdd(&hcnt[pairs[e].y & 255], 1);
    __syncthreads();
    // inclusive scan of hcnt
    for (int off = 1; off < 256; off <<= 1) {
        int t = (threadIdx.x >= off) ? hcnt[threadIdx.x - off] : 0;
        __syncthreads();
        if (threadIdx.x >= off) hcnt[threadIdx.x] += t;
        __syncthreads();
    }
    int offv = (threadIdx.x == 0) ? 0 : hcnt[threadIdx.x - 1];
    hcur[threadIdx.x] = offv;
    int node = (b << 8) + threadIdx.x;
    if (node < N_NODES) rowptr[node] = start + offv;
    if (b == NB - 1 && threadIdx.x == 0) rowptr[N_NODES] = endv;
    __syncthreads();
    for (int e = start + threadIdx.x; e < endv; e += 256) {
        int2 p = pairs[e];
        int pos = atomicAdd(&hcur[p.y & 255], 1);
        colidx[start + pos] = p.x;
    }
}

// ---------------------------------------------------------------------------
// Layer-1 aggregate: mean over bf16 neighbor rows (128ch), fp32 accum,
// bf16 out. 16 lanes per node, 16 nodes per 256-thread block.
// ---------------------------------------------------------------------------
__global__ __launch_bounds__(256) void agg1_kernel(
    const unsigned short* __restrict__ feat, const int* __restrict__ rowptr,
    const int* __restrict__ colidx, unsigned short* __restrict__ outp)
{
    const int node = blockIdx.x * 16 + (threadIdx.x >> 4);
    const int lane = threadIdx.x & 15;
    if (node >= N_NODES) return;
    const int beg = rowptr[node];
    const int end = rowptr[node + 1];

    float acc[8] = {};
    int i = beg;
    for (; i + 1 < end; i += 2) {
        int s0 = colidx[i], s1 = colidx[i + 1];
        int4 v0 = *reinterpret_cast<const int4*>(feat + (size_t)s0 * IN_CH + lane * 8);
        int4 v1 = *reinterpret_cast<const int4*>(feat + (size_t)s1 * IN_CH + lane * 8);
        acc[0] += bf16lo_f32(v0.x); acc[1] += bf16hi_f32(v0.x);
        acc[2] += bf16lo_f32(v0.y); acc[3] += bf16hi_f32(v0.y);
        acc[4] += bf16lo_f32(v0.z); acc[5] += bf16hi_f32(v0.z);
        acc[6] += bf16lo_f32(v0.w); acc[7] += bf16hi_f32(v0.w);
        acc[0] += bf16lo_f32(v1.x); acc[1] += bf16hi_f32(v1.x);
        acc[2] += bf16lo_f32(v1.y); acc[3] += bf16hi_f32(v1.y);
        acc[4] += bf16lo_f32(v1.z); acc[5] += bf16hi_f32(v1.z);
        acc[6] += bf16lo_f32(v1.w); acc[7] += bf16hi_f32(v1.w);
    }
    if (i < end) {
        int s0 = colidx[i];
        int4 v0 = *reinterpret_cast<const int4*>(feat + (size_t)s0 * IN_CH + lane * 8);
        acc[0] += bf16lo_f32(v0.x); acc[1] += bf16hi_f32(v0.x);
        acc[2] += bf16lo_f32(v0.y); acc[3] += bf16hi_f32(v0.y);
        acc[4] += bf16lo_f32(v0.z); acc[5] += bf16hi_f32(v0.z);
        acc[6] += bf16lo_f32(v0.w); acc[7] += bf16hi_f32(v0.w);
    }
    const float sc = 1.0f / fmaxf((float)(end - beg), 1.0f);
    alignas(16) unsigned short t[8];
#pragma unroll
    for (int j = 0; j < 8; ++j) t[j] = f32_bf16_rne(acc[j] * sc);
    *reinterpret_cast<int4*>(outp + (size_t)node * IN_CH + lane * 8) =
        *reinterpret_cast<const int4*>(t);
}

// ---------------------------------------------------------------------------
// Layer-2 aggregate: out(f32) += mean over bf16 rows of p (128ch).
// ---------------------------------------------------------------------------
__global__ __launch_bounds__(256) void agg2_kernel(
    const unsigned short* __restrict__ feat, const int* __restrict__ rowptr,
    const int* __restrict__ colidx, float* __restrict__ out)
{
    const int node = blockIdx.x * 16 + (threadIdx.x >> 4);
    const int lane = threadIdx.x & 15;
    if (node >= N_NODES) return;
    const int beg = rowptr[node];
    const int end = rowptr[node + 1];

    float acc[8] = {};
    int i = beg;
    for (; i + 1 < end; i += 2) {
        int s0 = colidx[i], s1 = colidx[i + 1];
        int4 v0 = *reinterpret_cast<const int4*>(feat + (size_t)s0 * OUT_CH + lane * 8);
        int4 v1 = *reinterpret_cast<const int4*>(feat + (size_t)s1 * OUT_CH + lane * 8);
        acc[0] += bf16lo_f32(v0.x); acc[1] += bf16hi_f32(v0.x);
        acc[2] += bf16lo_f32(v0.y); acc[3] += bf16hi_f32(v0.y);
        acc[4] += bf16lo_f32(v0.z); acc[5] += bf16hi_f32(v0.z);
        acc[6] += bf16lo_f32(v0.w); acc[7] += bf16hi_f32(v0.w);
        acc[0] += bf16lo_f32(v1.x); acc[1] += bf16hi_f32(v1.x);
        acc[2] += bf16lo_f32(v1.y); acc[3] += bf16hi_f32(v1.y);
        acc[4] += bf16lo_f32(v1.z); acc[5] += bf16hi_f32(v1.z);
        acc[6] += bf16lo_f32(v1.w); acc[7] += bf16hi_f32(v1.w);
    }
    if (i < end) {
        int s0 = colidx[i];
        int4 v0 = *reinterpret_cast<const int4*>(feat + (size_t)s0 * OUT_CH + lane * 8);
        acc[0] += bf16lo_f32(v0.x); acc[1] += bf16hi_f32(v0.x);
        acc[2] += bf16lo_f32(v0.y); acc[3] += bf16hi_f32(v0.y);
        acc[4] += bf16lo_f32(v0.z); acc[5] += bf16hi_f32(v0.z);
        acc[6] += bf16lo_f32(v0.w); acc[7] += bf16hi_f32(v0.w);
    }
    const float sc = 1.0f / fmaxf((float)(end - beg), 1.0f);
    float* o = out + (size_t)node * OUT_CH + lane * 8;
    float4 o0 = reinterpret_cast<float4*>(o)[0];
    float4 o1 = reinterpret_cast<float4*>(o)[1];
    o0.x += acc[0] * sc; o0.y += acc[1] * sc; o0.z += acc[2] * sc; o0.w += acc[3] * sc;
    o1.x += acc[4] * sc; o1.y += acc[5] * sc; o1.z += acc[6] * sc; o1.w += acc[7] * sc;
    reinterpret_cast<float4*>(o)[0] = o0;
    reinterpret_cast<float4*>(o)[1] = o1;
}

// ---------------------------------------------------------------------------
// MFMA GEMM pieces (unchanged from round 3). Block = 4 waves (2x2), block
// tile 128x128, wave tile 64x64, mfma_f32_16x16x32_bf16.
// ---------------------------------------------------------------------------
__device__ __forceinline__ void stage64(
    const unsigned short* __restrict__ g, int ldg, int rowBase, int maxRow,
    int kBase, unsigned short* __restrict__ s, int tid)
{
#pragma unroll
    for (int it = 0; it < 4; ++it) {
        int c = tid + it * 256;
        int r = c >> 3;
        int off = (c & 7) * 8;
        int row = rowBase + r;
        if (row >= maxRow) row = maxRow - 1;
        int4 v = *reinterpret_cast<const int4*>(g + (size_t)row * ldg + kBase + off);
        *reinterpret_cast<int4*>(s + r * LSTR + off) = v;
    }
}

__device__ __forceinline__ void mfma_tile(
    const unsigned short* __restrict__ As, const unsigned short* __restrict__ Bs,
    int wm, int wn, int l16, int quad, f32x4 acc[4][4])
{
#pragma unroll
    for (int k0 = 0; k0 < 64; k0 += 32) {
        bf16x8 a[4], b[4];
#pragma unroll
        for (int i = 0; i < 4; ++i)
            a[i] = *reinterpret_cast<const bf16x8*>(
                As + (wm * 64 + i * 16 + l16) * LSTR + k0 + quad * 8);
#pragma unroll
        for (int j = 0; j < 4; ++j)
            b[j] = *reinterpret_cast<const bf16x8*>(
                Bs + (wn * 64 + j * 16 + l16) * LSTR + k0 + quad * 8);
#pragma unroll
        for (int i = 0; i < 4; ++i)
#pragma unroll
            for (int j = 0; j < 4; ++j)
                acc[i][j] = __builtin_amdgcn_mfma_f32_16x16x32_bf16(
                    a[i], b[j], acc[i][j], 0, 0, 0);
    }
}

__global__ __launch_bounds__(256) void gemm1_mfma(
    const unsigned short* __restrict__ mean1b, const unsigned short* __restrict__ xb,
    const unsigned short* __restrict__ W1lb,   const unsigned short* __restrict__ W1rb,
    const float* __restrict__ b1l, unsigned short* __restrict__ hb)
{
    __shared__ unsigned short As[128 * LSTR];
    __shared__ unsigned short Bs[128 * LSTR];
    const int tid = threadIdx.x;
    const int wid = tid >> 6, lane = tid & 63;
    const int wm = wid & 1, wn = wid >> 1;
    const int l16 = lane & 15, quad = lane >> 4;
    const int rowBase = blockIdx.x * 128;
    const int colBase = blockIdx.y * 128;

    f32x4 z = {0.f, 0.f, 0.f, 0.f};
    f32x4 acc[4][4];
#pragma unroll
    for (int i = 0; i < 4; ++i)
#pragma unroll
        for (int j = 0; j < 4; ++j) acc[i][j] = z;

#pragma unroll
    for (int op = 0; op < 2; ++op) {
        const unsigned short* A = op ? xb : mean1b;
        const unsigned short* B = op ? W1rb : W1lb;
#pragma unroll
        for (int kb = 0; kb < IN_CH; kb += 64) {
            __syncthreads();
            stage64(A, IN_CH, rowBase, N_NODES, kb, As, tid);
            stage64(B, IN_CH, colBase, HID_CH, kb, Bs, tid);
            __syncthreads();
            mfma_tile(As, Bs, wm, wn, l16, quad, acc);
        }
    }

#pragma unroll
    for (int j = 0; j < 4; ++j) {
        int col = colBase + wn * 64 + j * 16 + l16;
        float bv = b1l[col];
#pragma unroll
        for (int i = 0; i < 4; ++i) {
            int mBase = rowBase + wm * 64 + i * 16 + quad * 4;
#pragma unroll
            for (int r = 0; r < 4; ++r) {
                int m = mBase + r;
                if (m < N_NODES) {
                    float v = fmaxf(acc[i][j][r] + bv, 0.0f);
                    hb[(size_t)m * HID_CH + col] = f32_bf16_rne(v);
                }
            }
        }
    }
}

__global__ __launch_bounds__(256) void gemm2_mfma(
    const unsigned short* __restrict__ hb, const unsigned short* __restrict__ W2lb,
    const unsigned short* __restrict__ W2rb, const float* __restrict__ b2l,
    unsigned short* __restrict__ pb, float* __restrict__ out)
{
    __shared__ unsigned short As[128 * LSTR];
    __shared__ unsigned short Bs[128 * LSTR];
    const int tid = threadIdx.x;
    const int wid = tid >> 6, lane = tid & 63;
    const int wm = wid & 1, wn = wid >> 1;
    const int l16 = lane & 15, quad = lane >> 4;
    const int rowBase = blockIdx.x * 128;
    const unsigned short* B = blockIdx.y ? W2rb : W2lb;

    f32x4 z = {0.f, 0.f, 0.f, 0.f};
    f32x4 acc[4][4];
#pragma unroll
    for (int i = 0; i < 4; ++i)
#pragma unroll
        for (int j = 0; j < 4; ++j) acc[i][j] = z;

#pragma unroll
    for (int kb = 0; kb < HID_CH; kb += 64) {
        __syncthreads();
        stage64(hb, HID_CH, rowBase, N_NODES, kb, As, tid);
        stage64(B, HID_CH, 0, OUT_CH, kb, Bs, tid);
        __syncthreads();
        mfma_tile(As, Bs, wm, wn, l16, quad, acc);
    }

    if (blockIdx.y == 0) {
#pragma unroll
        for (int j = 0; j < 4; ++j) {
            int col = wn * 64 + j * 16 + l16;
#pragma unroll
            for (int i = 0; i < 4; ++i) {
                int mBase = rowBase + wm * 64 + i * 16 + quad * 4;
#pragma unroll
                for (int r = 0; r < 4; ++r) {
                    int m = mBase + r;
                    if (m < N_NODES)
                        pb[(size_t)m * OUT_CH + col] = f32_bf16_rne(acc[i][j][r]);
                }
            }
        }
    } else {
#pragma unroll
        for (int j = 0; j < 4; ++j) {
            int col = wn * 64 + j * 16 + l16;
            float bv = b2l[col];
#pragma unroll
            for (int i = 0; i < 4; ++i) {
                int mBase = rowBase + wm * 64 + i * 16 + quad * 4;
#pragma unroll
                for (int r = 0; r < 4; ++r) {
                    int m = mBase + r;
                    if (m < N_NODES)
                        out[(size_t)m * OUT_CH + col] = acc[i][j][r] + bv;
                }
            }
        }
    }
}

extern "C" void kernel_launch(void* const* d_in, const int* in_sizes, int n_in,
                              void* d_out, int out_size, void* d_ws, size_t ws_size,
                              hipStream_t stream)
{
    const float* x   = (const float*)d_in[0];
    const int*   ei  = (const int*)d_in[1];
    const float* W1l = (const float*)d_in[2];
    const float* b1l = (const float*)d_in[3];
    const float* W1r = (const float*)d_in[4];
    const float* W2l = (const float*)d_in[5];
    const float* b2l = (const float*)d_in[6];
    const float* W2r = (const float*)d_in[7];

    const int E = in_sizes[1] / 2;
    const int* src = ei;
    const int* dst = ei + E;

    char* ws = (char*)d_ws;
    size_t off = 0;
    auto alloc = [&](size_t bytes) {
        void* p = ws + off;
        off += (bytes + 255) & ~(size_t)255;
        return p;
    };
    unsigned short* xb     = (unsigned short*)alloc((size_t)N_NODES * IN_CH * 2);
    unsigned short* mean1b = (unsigned short*)alloc((size_t)N_NODES * IN_CH * 2);
    unsigned short* hb     = (unsigned short*)alloc((size_t)N_NODES * HID_CH * 2);
    unsigned short* pb     = (unsigned short*)alloc((size_t)N_NODES * OUT_CH * 2);
    unsigned short* W1lb   = (unsigned short*)alloc((size_t)HID_CH * IN_CH * 2);
    unsigned short* W1rb   = (unsigned short*)alloc((size_t)HID_CH * IN_CH * 2);
    unsigned short* W2lb   = (unsigned short*)alloc((size_t)OUT_CH * HID_CH * 2);
    unsigned short* W2rb   = (unsigned short*)alloc((size_t)OUT_CH * HID_CH * 2);
    int*  counts = (int*)alloc((size_t)NBNW * 4);
    int*  S      = (int*)alloc((size_t)(NBNW + 1) * 4);
    int*  bsum   = (int*)alloc((size_t)256 * 4);
    int*  boff   = (int*)alloc((size_t)256 * 4);
    int2* pairs  = (int2*)alloc((size_t)E * 8);
    int*  rowptr = (int*)alloc((size_t)(N_NODES + 1) * 4);
    int*  colidx = (int*)alloc((size_t)E * 4);
    float* out = (float*)d_out;

    const int chunk = (E + NWG - 1) / NWG;
    const int nbS = (NBNW + 255) / 256;   // 49

    // CSR build: two-level counting sort
    bcount_kernel<<<NWG, 256, 0, stream>>>(src, dst, counts, E, chunk);
    scanA_kernel<<<nbS, 256, 0, stream>>>(counts, S, bsum);
    scanB_kernel<<<1, 256, 0, stream>>>(bsum, boff, nbS);
    scanC_kernel<<<nbS, 256, 0, stream>>>(S, boff, counts);
    bscatter_kernel<<<NWG, 256, 0, stream>>>(src, dst, S, pairs, E, chunk);
    bsort_kernel<<<NB, 256, 0, stream>>>(pairs, S, rowptr, colidx);

    // bf16 conversions
    const int xn8 = N_NODES * IN_CH / 8;
    cvt_bf16_kernel<<<(xn8 + 255) / 256, 256, 0, stream>>>(x, xb, xn8);
    const int wn8 = HID_CH * IN_CH / 8;   // 4096 per matrix
    cvt4_bf16_kernel<<<(4 * wn8 + 255) / 256, 256, 0, stream>>>(
        W1l, W1r, W2l, W2r, W1lb, W1rb, W2lb, W2rb, wn8);

    const int aggBlocks = (N_NODES + 15) / 16;
    const int mBlocks = (N_NODES + 127) / 128;   // 391

    // Layer 1
    agg1_kernel<<<aggBlocks, 256, 0, stream>>>(xb, rowptr, colidx, mean1b);
    gemm1_mfma<<<dim3(mBlocks, HID_CH / 128), 256, 0, stream>>>(
        mean1b, xb, W1lb, W1rb, b1l, hb);

    // Layer 2 (transform-then-aggregate)
    gemm2_mfma<<<dim3(mBlocks, 2), 256, 0, stream>>>(hb, W2lb, W2rb, b2l, pb, out);
    agg2_kernel<<<aggBlocks, 256, 0, stream>>>(pb, rowptr, colidx, out);
}